// Round 8
// baseline (584.970 us; speedup 1.0000x reference)
//
#include <hip/hip_runtime.h>
#include <hip/hip_bf16.h>

#define N_NODES 100000
#define N_EDGES 1600000
#define OUTF 128
#define INF 256
#define SCAN_CHUNK 1024
#define SCAN_BLOCKS 98   // 98*1024 = 100352 >= 100000
#define M_TILES 6250     // 100000 / 16

#define P_PART 64        // edge partitions (1 block each, private histogram slice)
#define EDGES_PER_PART 25000  // 64 * 25000 = 1.6M exactly
#define PROJ_BLOCKS 2500

typedef _Float16 f16;
typedef _Float16 half8 __attribute__((ext_vector_type(8)));
typedef _Float16 half2v __attribute__((ext_vector_type(2)));
typedef float floatx4 __attribute__((ext_vector_type(4)));

// ---------------- fused: partition-private histogram + W->Bt convert ----------------
// R8: replaces the 1.6M device-scope atomicAdd count_rank (~170 us by time algebra:
// agent-scope atomics execute at the fabric coherence point, ~4 ops/cycle chip-wide).
// Block p owns edges [25000p, +25000) and histogram slice cnt[p][0..N): zero it,
// then count with WORKGROUP-scope atomics -- legal (slice is block-private) and
// executed in the XCD-local L2 (fast RMW, no cross-die coherence round trip).
// blocks [P_PART, P_PART+256): convert_B role (Bt layout as before).
__global__ __launch_bounds__(256) void hist_convB_kernel(const int* __restrict__ dst,
                                                         int* __restrict__ cnt,
                                                         const float* __restrict__ Wm,
                                                         const float* __restrict__ Wv,
                                                         f16* __restrict__ Bt) {
    int bid = blockIdx.x;
    int t = threadIdx.x;
    if (bid >= P_PART) {
        int ng = bid - P_PART;
        int g = ng >> 4, i = ng & 15;
        int ch = g >> 3, wl = (g >> 1) & 3, cg = g & 1;
        int col = ch * 64 + wl * 16 + i;
        const float* srcW = cg ? Wv : Wm;
        Bt[ng * 256 + t] = (f16)srcW[t * 128 + col];
        return;
    }
    int* my = cnt + (size_t)bid * N_NODES;
    // zero own slice (100000 ints = 25000 int4), visible in local L2 before atomics
    for (int i = t; i < 25000; i += 256) ((int4*)my)[i] = make_int4(0, 0, 0, 0);
    __syncthreads(); // compiler drains stores (vmcnt) before barrier

    int base = bid * EDGES_PER_PART;
    for (int i = base + t; i < base + EDGES_PER_PART; i += 256) {
        __hip_atomic_fetch_add(&my[dst[i]], 1, __ATOMIC_RELAXED,
                               __HIP_MEMORY_SCOPE_WORKGROUP);
    }
}

// ---------------- column scan: exclusive prefix over partitions + deg + partials ----
// For each node d: cnt[p][d] <- sum_{q<p} count[q][d] (in place), deg[d] = total.
// Also emits per-1024-chunk sums (same chunking as scan_final) for the top scan.
__global__ __launch_bounds__(256) void colscan_kernel(int* __restrict__ cnt, int n,
                                                      int* __restrict__ deg,
                                                      int* __restrict__ partial) {
    __shared__ int red[256];
    int b = blockIdx.x, t = threadIdx.x;
    int d0 = b * SCAN_CHUNK + t * 4;
    int tsum = 0;
    if (d0 < n) { // n % 4 == 0 -> all 4 lanes of the int4 valid
        int4 acc = make_int4(0, 0, 0, 0);
#pragma unroll 4
        for (int p = 0; p < P_PART; p++) {
            int4* ptr = (int4*)(cnt + (size_t)p * N_NODES + d0);
            int4 v = *ptr;
            *ptr = acc;
            acc.x += v.x; acc.y += v.y; acc.z += v.z; acc.w += v.w;
        }
        *(int4*)(deg + d0) = acc;
        tsum = acc.x + acc.y + acc.z + acc.w;
    }
    red[t] = tsum;
    __syncthreads();
    for (int off = 128; off > 0; off >>= 1) {
        if (t < off) red[t] += red[t + off];
        __syncthreads();
    }
    if (t == 0) partial[b] = red[0];
}

// ---------------- scan step 2: exclusive scan of partials (nb <= 128) ----------------
__global__ __launch_bounds__(128) void scan_top_kernel(int* __restrict__ partial, int nb,
                                                       int* __restrict__ row_start, int n) {
    __shared__ int sc[128];
    int t = threadIdx.x;
    int v = (t < nb) ? partial[t] : 0;
    sc[t] = v;
    __syncthreads();
    for (int off = 1; off < 128; off <<= 1) {
        int val = sc[t];
        int add = (t >= off) ? sc[t - off] : 0;
        __syncthreads();
        sc[t] = val + add;
        __syncthreads();
    }
    if (t < nb) partial[t] = sc[t] - v;   // exclusive
    if (t == 127) row_start[n] = sc[127]; // total edge count
}

// ---------------- scan step 3: per-chunk exclusive scan + norms ----------------
__global__ __launch_bounds__(256) void scan_final_kernel(const int* __restrict__ deg, int n,
                                                         const int* __restrict__ partial,
                                                         int* __restrict__ row_start,
                                                         float* __restrict__ norm1,
                                                         float* __restrict__ norm2) {
    __shared__ int sc[256];
    int b = blockIdx.x, t = threadIdx.x;
    int base = b * SCAN_CHUNK + t * 4;
    int v[4];
    int tsum = 0;
#pragma unroll
    for (int j = 0; j < 4; j++) {
        int idx = base + j;
        v[j] = (idx < n) ? deg[idx] : 0;
        tsum += v[j];
    }
    sc[t] = tsum;
    __syncthreads();
    for (int off = 1; off < 256; off <<= 1) {
        int val = sc[t];
        int add = (t >= off) ? sc[t - off] : 0;
        __syncthreads();
        sc[t] = val + add;
        __syncthreads();
    }
    int run = sc[t] - tsum + partial[b];
#pragma unroll
    for (int j = 0; j < 4; j++) {
        int idx = base + j;
        if (idx < n) {
            row_start[idx] = run;
            float d = (float)(v[j] > 0 ? v[j] : 1); // clip(deg, 1)
            norm1[idx] = rsqrtf(d);
            norm2[idx] = 1.0f / d;
            run += v[j];
        }
    }
}

// ---------------- fused MFMA projection + CSR edge scatter (counting-sort phase 2) --
// blocks [0, P_PART): scatter role, dispatched FIRST so they grab CUs early and
// hide under proj. Block p re-reads its edge partition; slot handout via
// workgroup-scope atomicAdd on its private cnt[p][d] (now the exclusive prefix):
// pos = row_start[d] + prefix + local_rank. No agent-scope atomics anywhere.
// blocks [P_PART, +2500): proj role, R5-verbatim (best measured).
__global__ __launch_bounds__(256, 3) void proj_scatter_kernel(
        const float* __restrict__ feat, const f16* __restrict__ Bt,
        const float* __restrict__ norm1, const float* __restrict__ norm2,
        f16* __restrict__ msg,
        const int* __restrict__ src, const int* __restrict__ dst,
        const int* __restrict__ row_start, int* __restrict__ cnt,
        int* __restrict__ srcs_sorted) {
    __shared__ float As[2][16 * 256]; // 2 x 16 KB double buffer (proj role)

    int bid = blockIdx.x;
    if (bid < P_PART) {
        // ---- scatter role ----
        int* my = cnt + (size_t)bid * N_NODES;
        int base = bid * EDGES_PER_PART;
        for (int i = base + threadIdx.x; i < base + EDGES_PER_PART; i += 256) {
            int d = dst[i];
            int pos = row_start[d] +
                      __hip_atomic_fetch_add(&my[d], 1, __ATOMIC_RELAXED,
                                             __HIP_MEMORY_SCOPE_WORKGROUP);
            srcs_sorted[pos] = src[i];
        }
        return;
    }

    // ---- proj role (R5-verbatim) ----
    int proj_id = bid - P_PART;
    int tid = threadIdx.x;
    int w = tid >> 6;
    int lane = tid & 63;
    int quad = lane >> 4;
    int l15 = lane & 15;
    int ch = proj_id & 1;
    int tbase = proj_id >> 1; // 0..1249

    // load B fragments once: 2 col-groups (mean/var, same 16 cols) x 8 k-frags
    half8 b[2][8];
#pragma unroll
    for (int cg = 0; cg < 2; cg++) {
        int g = ch * 8 + w * 2 + cg;
        const f16* bp = Bt + (size_t)(g * 16 + l15) * 256 + quad * 8;
#pragma unroll
        for (int kf = 0; kf < 8; kf++) {
            b[cg][kf] = *(const half8*)(bp + kf * 32);
        }
    }
    // pin: forces register residency across the loop (R2 evidence: VGPR=84 kept B)
#pragma unroll
    for (int cg = 0; cg < 2; cg++) {
#pragma unroll
        for (int kf = 0; kf < 8; kf++) {
            asm volatile("" : "+v"(b[cg][kf]));
        }
    }

    int col = ch * 64 + w * 16 + l15; // 0..127

    // swizzled ds_read byte addresses (row = l15): slot = X ^ ((row&7)<<4)
    int swz = (l15 & 7) << 4;
    int rb0 = l15 * 1024 + ((quad * 32) ^ swz);
    int rb1 = l15 * 1024 + ((quad * 32 + 16) ^ swz);
    int lsw = lane * 16;

    // wave w stages rows w*4 .. w*4+3 of each tile (1 KB per instruction)
    auto stage = [&](int buf, int t) {
        int m0 = t * 16;
#pragma unroll
        for (int j = 0; j < 4; j++) {
            int r = w * 4 + j;
            const char* gp = (const char*)(feat + (size_t)(m0 + r) * 256)
                             + (lsw ^ ((r & 7) << 4));
            char* lp = (char*)&As[buf][0] + r * 1024; // wave-uniform base
            __builtin_amdgcn_global_load_lds(
                (const __attribute__((address_space(1))) void*)gp,
                (__attribute__((address_space(3))) void*)lp, 16, 0, 0);
        }
    };

    stage(0, tbase);
    int cur = 0;

    for (int t = tbase; t < M_TILES; t += 1250) {
        __syncthreads(); // drains staging of buf[cur]

        int tn = t + 1250;
        if (tn < M_TILES) stage(cur ^ 1, tn); // in flight under this tile's compute

        const char* ab = (const char*)&As[cur][0];
        half8 a[8];
#pragma unroll
        for (int kf = 0; kf < 8; kf++) {
            floatx4 f0 = *(const floatx4*)(ab + rb0 + kf * 128);
            floatx4 f1 = *(const floatx4*)(ab + rb1 + kf * 128);
            half8 h;
            h[0] = (f16)f0.x; h[1] = (f16)f0.y; h[2] = (f16)f0.z; h[3] = (f16)f0.w;
            h[4] = (f16)f1.x; h[5] = (f16)f1.y; h[6] = (f16)f1.z; h[7] = (f16)f1.w;
            a[kf] = h;
        }

        int m0 = t * 16;
        float s1r[4], s2r[4];
#pragma unroll
        for (int r = 0; r < 4; r++) {
            int node = m0 + quad * 4 + r;
            s1r[r] = norm1[node];
            s2r[r] = norm2[node];
        }

        floatx4 acc0 = (floatx4){0.f, 0.f, 0.f, 0.f};
        floatx4 acc1 = (floatx4){0.f, 0.f, 0.f, 0.f};
#pragma unroll
        for (int kf = 0; kf < 8; kf++) {
            acc0 = __builtin_amdgcn_mfma_f32_16x16x32_f16(a[kf], b[0][kf], acc0, 0, 0, 0);
            acc1 = __builtin_amdgcn_mfma_f32_16x16x32_f16(a[kf], b[1][kf], acc1, 0, 0, 0);
        }

        // epilogue: paired (m,v) 4 B stores, norms applied here
#pragma unroll
        for (int r = 0; r < 4; r++) {
            int node = m0 + quad * 4 + r;
            float m = fmaxf(acc0[r], 0.f);
            float v = fmaxf(acc1[r], 0.f);
            float att = __expf(-v); // GAMMA = 1
            half2v pr;
            pr[0] = (f16)(m * att * s1r[r]);
            pr[1] = (f16)(v * att * att * s2r[r]);
            *(half2v*)(msg + (size_t)node * 256 + col * 2) = pr;
        }
        cur ^= 1;
    }
}

// ---------------- per-dst aggregation (wave per dst) + final norm (R5-verbatim) -----
// Half-wave parity split; lane jc loads one half8 (16 B = cols 4jc..4jc+3 as (m,v)
// pairs) per edge, 4 edges in flight; shfl_xor(32) combine; nontemporal out stores.
// R4-R7 verdict: traffic-bound at ~4.1 TB/s / 491 MB -- near its floor.
__global__ __launch_bounds__(256) void agg_kernel(const int* __restrict__ row_start,
                                                  const int* __restrict__ srcs,
                                                  const f16* __restrict__ msg,
                                                  const float* __restrict__ norm1,
                                                  const float* __restrict__ norm2,
                                                  float* __restrict__ out_mean,
                                                  float* __restrict__ out_var) {
    int d = blockIdx.x * 4 + (threadIdx.x >> 6);
    int lane = threadIdx.x & 63;
    int half = lane >> 5;   // 0: even edges, 1: odd edges
    int jc = lane & 31;     // col group: cols 4jc..4jc+3

    int s0 = row_start[d];
    int s1 = row_start[d + 1];

    float am0 = 0.f, am1 = 0.f, am2 = 0.f, am3 = 0.f;
    float av0 = 0.f, av1 = 0.f, av2 = 0.f, av3 = 0.f;

    int i = s0 + half;
    for (; i + 6 < s1; i += 8) {
        int sa = srcs[i], sb = srcs[i + 2], sc = srcs[i + 4], sd = srcs[i + 6];
        half8 ha = *(const half8*)(msg + (size_t)sa * 256 + jc * 8);
        half8 hb = *(const half8*)(msg + (size_t)sb * 256 + jc * 8);
        half8 hc = *(const half8*)(msg + (size_t)sc * 256 + jc * 8);
        half8 hd = *(const half8*)(msg + (size_t)sd * 256 + jc * 8);
        am0 += (float)ha[0] + (float)hb[0] + (float)hc[0] + (float)hd[0];
        av0 += (float)ha[1] + (float)hb[1] + (float)hc[1] + (float)hd[1];
        am1 += (float)ha[2] + (float)hb[2] + (float)hc[2] + (float)hd[2];
        av1 += (float)ha[3] + (float)hb[3] + (float)hc[3] + (float)hd[3];
        am2 += (float)ha[4] + (float)hb[4] + (float)hc[4] + (float)hd[4];
        av2 += (float)ha[5] + (float)hb[5] + (float)hc[5] + (float)hd[5];
        am3 += (float)ha[6] + (float)hb[6] + (float)hc[6] + (float)hd[6];
        av3 += (float)ha[7] + (float)hb[7] + (float)hc[7] + (float)hd[7];
    }
    for (; i < s1; i += 2) {
        int sa = srcs[i];
        half8 ha = *(const half8*)(msg + (size_t)sa * 256 + jc * 8);
        am0 += (float)ha[0];
        av0 += (float)ha[1];
        am1 += (float)ha[2];
        av1 += (float)ha[3];
        am2 += (float)ha[4];
        av2 += (float)ha[5];
        am3 += (float)ha[6];
        av3 += (float)ha[7];
    }

    am0 += __shfl_xor(am0, 32, 64);
    am1 += __shfl_xor(am1, 32, 64);
    am2 += __shfl_xor(am2, 32, 64);
    am3 += __shfl_xor(am3, 32, 64);
    av0 += __shfl_xor(av0, 32, 64);
    av1 += __shfl_xor(av1, 32, 64);
    av2 += __shfl_xor(av2, 32, 64);
    av3 += __shfl_xor(av3, 32, 64);

    if (half == 0) {
        float k1 = norm1[d], k2 = norm2[d];
        floatx4 om = {am0 * k1, am1 * k1, am2 * k1, am3 * k1};
        floatx4 ov = {av0 * k2, av1 * k2, av2 * k2, av3 * k2};
        __builtin_nontemporal_store(om, (floatx4*)(out_mean + (size_t)d * 128 + jc * 4));
        __builtin_nontemporal_store(ov, (floatx4*)(out_var + (size_t)d * 128 + jc * 4));
    }
}

extern "C" void kernel_launch(void* const* d_in, const int* in_sizes, int n_in,
                              void* d_out, int out_size, void* d_ws, size_t ws_size,
                              hipStream_t stream) {
    const float* feat = (const float*)d_in[0];
    const float* Wm = (const float*)d_in[1];
    const float* Wv = (const float*)d_in[2];
    const int* src = (const int*)d_in[3];
    const int* dst = (const int*)d_in[4];
    float* out = (float*)d_out;

    const int N = N_NODES;

    char* wsp = (char*)d_ws;
    auto carve = [&](size_t bytes) {
        char* p = wsp;
        wsp += (bytes + 255) & ~(size_t)255;
        return p;
    };
    f16* msg = (f16*)carve((size_t)N * 256 * sizeof(f16));        // (m,v) pairs, 51.2 MB
    f16* Bt = (f16*)carve((size_t)256 * 256 * sizeof(f16));       // 128 KB
    int* srcs_sorted = (int*)carve((size_t)N_EDGES * 4);          // 6.4 MB
    int* cnt = (int*)carve((size_t)P_PART * N_NODES * 4);         // 25.6 MB (self-zeroed)
    int* deg = (int*)carve((size_t)N * 4);
    int* row_start = (int*)carve((size_t)(N + 1) * 4);
    float* norm1 = (float*)carve((size_t)N * 4);
    float* norm2 = (float*)carve((size_t)N * 4);
    int* partial = (int*)carve(128 * 4);

    // no memset needed: cnt zeroed in-kernel, deg written by colscan before reads
    hist_convB_kernel<<<P_PART + 256, 256, 0, stream>>>(dst, cnt, Wm, Wv, Bt);
    colscan_kernel<<<SCAN_BLOCKS, 256, 0, stream>>>(cnt, N, deg, partial);
    scan_top_kernel<<<1, 128, 0, stream>>>(partial, SCAN_BLOCKS, row_start, N);
    scan_final_kernel<<<SCAN_BLOCKS, 256, 0, stream>>>(deg, N, partial, row_start,
                                                       norm1, norm2);
    proj_scatter_kernel<<<P_PART + PROJ_BLOCKS, 256, 0, stream>>>(
        feat, Bt, norm1, norm2, msg, src, dst, row_start, cnt, srcs_sorted);
    agg_kernel<<<N / 4, 256, 0, stream>>>(row_start, srcs_sorted, msg, norm1, norm2,
                                          out, out + (size_t)N * OUTF);
}